// Round 8
// baseline (179.882 us; speedup 1.0000x reference)
//
#include <hip/hip_runtime.h>
#include <hip/hip_bf16.h>

typedef __bf16 bf16x8 __attribute__((ext_vector_type(8)));
typedef float  f32x4  __attribute__((ext_vector_type(4)));
typedef float  f32x16 __attribute__((ext_vector_type(16)));

// async 16B global -> LDS (wave-uniform LDS base + lane*16)
__device__ __forceinline__ void gload_lds16(const void* g, void* l) {
  __builtin_amdgcn_global_load_lds(
      (const __attribute__((address_space(1))) unsigned int*)g,
      (__attribute__((address_space(3))) unsigned int*)l, 16, 0, 0);
}

// ---------------- fp32 -> bf16 convert (vectorized) ----------------
__global__ void k_cvt(const float* __restrict__ s, __bf16* __restrict__ d, int n4) {
  int i = blockIdx.x * blockDim.x + threadIdx.x;
  if (i >= n4) return;
  float4 v = ((const float4*)s)[i];
  union { __bf16 h[4]; uint2 u; } o;
  o.h[0] = (__bf16)v.x; o.h[1] = (__bf16)v.y;
  o.h[2] = (__bf16)v.z; o.h[3] = (__bf16)v.w;
  ((uint2*)d)[i] = o.u;
}

// ---------------- C[M,N] = A[M,K] @ B[N,K]^T + bias ----------------
// 128x64 tile, BK=32, 256 threads (4 waves 2x2). grid = 512 blocks. (proven, verbatim)
template<bool OUT_BF16>
__global__ __launch_bounds__(256, 2)
void k_gemm_bt(const __bf16* __restrict__ A, const __bf16* __restrict__ B,
               const float* __restrict__ bias, void* __restrict__ C,
               int M, int N, int K) {
  __shared__ __align__(16) __bf16 At[128 * 32];
  __shared__ __align__(16) __bf16 Bt[64 * 32];
  const int tid  = threadIdx.x;
  const int lane = tid & 63;
  const int w    = tid >> 6;
  const int wr   = w >> 1, wc = w & 1;
  const int bm   = blockIdx.y * 128, bn = blockIdx.x * 64;

  f32x4 acc[4][2] = {};

  const __bf16* ga = A + (size_t)(bm + (tid >> 2)) * K + (tid & 3) * 8;
  const __bf16* gb = B + (size_t)(bn + (tid >> 2)) * K + (tid & 3) * 8;

  for (int k0 = 0; k0 < K; k0 += 32) {
    __syncthreads();
    gload_lds16(ga + k0,                  &At[(w * 16) * 32]);
    gload_lds16(ga + k0 + (size_t)64 * K, &At[(64 + w * 16) * 32]);
    gload_lds16(gb + k0,                  &Bt[(w * 16) * 32]);
    __syncthreads();

    bf16x8 a[4], b[2];
#pragma unroll
    for (int mt = 0; mt < 4; ++mt)
      a[mt] = *(const bf16x8*)&At[(wr * 64 + mt * 16 + (lane & 15)) * 32 + (lane >> 4) * 8];
#pragma unroll
    for (int nt = 0; nt < 2; ++nt)
      b[nt] = *(const bf16x8*)&Bt[(wc * 32 + nt * 16 + (lane & 15)) * 32 + (lane >> 4) * 8];
    __builtin_amdgcn_s_setprio(1);
#pragma unroll
    for (int mt = 0; mt < 4; ++mt)
#pragma unroll
      for (int nt = 0; nt < 2; ++nt)
        acc[mt][nt] = __builtin_amdgcn_mfma_f32_16x16x32_bf16(a[mt], b[nt], acc[mt][nt], 0, 0, 0);
    __builtin_amdgcn_s_setprio(0);
  }

#pragma unroll
  for (int nt = 0; nt < 2; ++nt) {
    const int col = bn + wc * 32 + nt * 16 + (lane & 15);
    const float bv = bias[col];
#pragma unroll
    for (int mt = 0; mt < 4; ++mt) {
#pragma unroll
      for (int r = 0; r < 4; ++r) {
        const int row = bm + wr * 64 + mt * 16 + (lane >> 4) * 4 + r;
        const float v = acc[mt][nt][r] + bv;
        if (OUT_BF16) ((__bf16*)C)[(size_t)row * N + col] = (__bf16)v;
        else          ((float*)C)[(size_t)row * N + col]  = v;
      }
    }
  }
}

// ---------------- flash attention (Q = K = V), split-KV, 32x32x16 MFMA ----------------
// 512 threads = 8 waves. Wave pair (w, w+4) owns q-rows [q0, q0+32); w<4 consumes even
// KV tiles (buf 0), w>=4 odd tiles (buf 1). 16 supersteps stage a tile PAIR each.
// Staging: thread covers 2 adjacent kv rows (2m, 2m+1) of one tile -> Kt 2x b128,
// Vt transpose as 8 packed b32 (2-way bank = free). SWZ2 swizzle as round 7 (0 confl).
// Flash-merge epilogue combines the pair via LDS (aliases KV buffers).
#define SWZ2(row, col) ((row) * 64 + ((col) ^ (((((row) & 7) ^ ((row) >> 3)) & 7) << 3)))

__global__ __launch_bounds__(512, 4)
void k_attn(const __bf16* __restrict__ q, __bf16* __restrict__ o) {
  __shared__ __align__(16) __bf16 KVs[4][64 * 64];   // [0,1]=Kt even/odd, [2,3]=Vt even/odd (32KB)
  __shared__ float ml[4][2][64];                     // per upper-wave m,l
  float* obuf = (float*)&KVs[0][0];                  // merge buffer aliases KVs (32KB)

  const int tid = threadIdx.x, lane = tid & 63, w = tid >> 6;
  const int l31 = lane & 31, h = lane >> 5;
  const int hb = w >> 2;                             // tile parity this wave consumes
  const int bh = blockIdx.y;
  const size_t base = ((size_t)(bh >> 4) * 2048) * 1024 + (bh & 15) * 64;
  const int q0 = blockIdx.x * 128 + (w & 3) * 32;

  // Q B-frags: col q = q0+l31, k(d) = 16ks + 8h + 0..7
  bf16x8 qb[4];
#pragma unroll
  for (int ks = 0; ks < 4; ++ks)
    qb[ks] = *(const bf16x8*)&q[base + (size_t)(q0 + l31) * 1024 + ks * 16 + h * 8];

  f32x16 O[2] = {};                 // row q=(reg&3)+8*(reg>>2)+4h, col d=32dh+l31
  float m2 = -3e38f, l_run = 0.f;
  const float c2 = 0.18033688f;     // 0.125 * log2(e)

  // staging coords: threads 0-255 stage even tile, 256-511 odd tile
  const int st = tid & 255, tp = tid >> 8;
  const int sm = st >> 3, c0 = (st & 7) * 8;         // kv rows 2sm,2sm+1; cols c0..c0+7
  const __bf16* gsrc = q + base + (size_t)(tp * 64 + 2 * sm) * 1024 + c0;
  __bf16* myK = &KVs[tp][0];
  __bf16* myV = &KVs[2 + tp][0];
  const __bf16* cK = &KVs[hb][0];
  const __bf16* cV = &KVs[2 + hb][0];

  // prologue: superstep-0 pair into registers
  bf16x8 v0 = *(const bf16x8*)&gsrc[0];
  bf16x8 v1 = *(const bf16x8*)&gsrc[1024];

  for (int t = 0; t < 16; ++t) {
    __syncthreads();                                 // prior superstep's reads complete
    *(bf16x8*)&myK[SWZ2(2 * sm, c0)]     = v0;
    *(bf16x8*)&myK[SWZ2(2 * sm + 1, c0)] = v1;
#pragma unroll
    for (int j = 0; j < 8; ++j) {
      union { __bf16 b[2]; unsigned u; } pk;
      pk.b[0] = v0[j]; pk.b[1] = v1[j];
      *(unsigned*)&myV[SWZ2(c0 + j, 2 * sm)] = pk.u;
    }
    __syncthreads();                                 // pair visible

    if (t < 15) {                                    // prefetch next pair
      v0 = *(const bf16x8*)&gsrc[(size_t)(t + 1) * 128 * 1024];
      v1 = *(const bf16x8*)&gsrc[(size_t)(t + 1) * 128 * 1024 + 1024];
    }

    // ---- QK^T: S^T[kv, q], 64kv x 32q per wave, 8 mfma
    f32x16 s[2] = {};
#pragma unroll
    for (int kvf = 0; kvf < 2; ++kvf) {
#pragma unroll
      for (int ks = 0; ks < 4; ++ks) {
        bf16x8 ka = *(const bf16x8*)&cK[SWZ2(kvf * 32 + l31, ks * 16 + h * 8)];
        s[kvf] = __builtin_amdgcn_mfma_f32_32x32x16_bf16(ka, qb[ks], s[kvf], 0, 0, 0);
      }
    }

    // ---- online softmax (base-2, defer-rescale); lane's q = l31
    float mx = -3e38f;
#pragma unroll
    for (int kvf = 0; kvf < 2; ++kvf)
#pragma unroll
      for (int r = 0; r < 16; ++r)
        mx = fmaxf(mx, s[kvf][r]);
    mx = fmaxf(mx, __shfl_xor(mx, 32));
    mx *= c2;
    if (!__all(mx - m2 <= 5.77f)) {
      const float mnew = fmaxf(m2, mx);
      const float ps = exp2f(m2 - mnew);
      m2 = mnew;
      l_run *= ps;
#pragma unroll
      for (int r = 0; r < 16; ++r) {
        const int qrow = (r & 3) + 8 * (r >> 2) + 4 * h;
        const float rs = __shfl(ps, qrow);
        O[0][r] *= rs;
        O[1][r] *= rs;
      }
    }
    float lsum = 0.f;
    unsigned P[2][4][2];
#pragma unroll
    for (int kvf = 0; kvf < 2; ++kvf) {
#pragma unroll
      for (int rq = 0; rq < 4; ++rq) {
#pragma unroll
        for (int tt = 0; tt < 2; ++tt) {
          const float p0 = exp2f(fmaf(s[kvf][rq * 4 + tt * 2],     c2, -m2));
          const float p1 = exp2f(fmaf(s[kvf][rq * 4 + tt * 2 + 1], c2, -m2));
          lsum += p0 + p1;
          union { __bf16 b[2]; unsigned u; } pk;
          pk.b[0] = (__bf16)p0; pk.b[1] = (__bf16)p1;
          P[kvf][rq][tt] = pk.u;
        }
      }
    }
    lsum += __shfl_xor(lsum, 32);
    l_run += lsum;

    // lane^32 word exchange (P -> PV A-frag)
    unsigned R[2][2][2];
#pragma unroll
    for (int kvf = 0; kvf < 2; ++kvf)
#pragma unroll
      for (int k = 0; k < 2; ++k)
#pragma unroll
        for (int tt = 0; tt < 2; ++tt)
          R[kvf][k][tt] = (unsigned)__shfl_xor(
              (int)(h ? P[kvf][2 * k][tt] : P[kvf][2 * k + 1][tt]), 32);

    // ---- PV: O[q,d] += P[q,kv] V[kv,d]
#pragma unroll
    for (int dh = 0; dh < 2; ++dh) {
#pragma unroll
      for (int ko = 0; ko < 4; ++ko) {
        const int kvf = ko >> 1, k2 = (ko & 1) * 2, kk = ko & 1;
        union { unsigned u[4]; bf16x8 v; } pu;
        pu.u[0] = h ? R[kvf][kk][0]     : P[kvf][k2][0];
        pu.u[1] = h ? R[kvf][kk][1]     : P[kvf][k2][1];
        pu.u[2] = h ? P[kvf][k2 + 1][0] : R[kvf][kk][0];
        pu.u[3] = h ? P[kvf][k2 + 1][1] : R[kvf][kk][1];
        bf16x8 vb = *(const bf16x8*)&cV[SWZ2(dh * 32 + l31, ko * 16 + h * 8)];
        O[dh] = __builtin_amdgcn_mfma_f32_32x32x16_bf16(pu.v, vb, O[dh], 0, 0, 0);
      }
    }
  }

  // ---- flash-merge of wave pair (w, w+4), then store
  __syncthreads();                                   // all compute done; KVs free
  if (w >= 4) {
    ml[w - 4][0][lane] = m2;
    ml[w - 4][1][lane] = l_run;
#pragma unroll
    for (int dh = 0; dh < 2; ++dh)
#pragma unroll
      for (int r = 0; r < 16; ++r)
        obuf[(w - 4) * 2048 + (dh * 16 + r) * 64 + lane] = O[dh][r];
  }
  __syncthreads();
  if (w < 4) {
    const float mB = ml[w][0][lane], lB = ml[w][1][lane];
    const float mS = fmaxf(m2, mB);
    const float sA = exp2f(m2 - mS), sB = exp2f(mB - mS);
    const float linv = 1.0f / (l_run * sA + lB * sB);
    const float fA = sA * linv, fB = sB * linv;
#pragma unroll
    for (int r = 0; r < 16; ++r) {
      const int qrow = (r & 3) + 8 * (r >> 2) + 4 * h;
      const float rA = __shfl(fA, qrow), rB = __shfl(fB, qrow);
#pragma unroll
      for (int dh = 0; dh < 2; ++dh) {
        const float ov = O[dh][r] * rA + obuf[w * 2048 + (dh * 16 + r) * 64 + lane] * rB;
        o[base + (size_t)(q0 + qrow) * 1024 + dh * 32 + l31] = (__bf16)ov;
      }
    }
  }
}

// ---------------- launch ----------------
extern "C" void kernel_launch(void* const* d_in, const int* in_sizes, int n_in,
                              void* d_out, int out_size, void* d_ws, size_t ws_size,
                              hipStream_t stream) {
  const float* x  = (const float*)d_in[0];
  const float* Wq = (const float*)d_in[1];
  const float* bq = (const float*)d_in[2];
  const float* Wo = (const float*)d_in[3];
  const float* bo = (const float*)d_in[4];

  char* ws = (char*)d_ws;
  __bf16* xb  = (__bf16*)(ws);                          // 8 MB  [4096,1024]
  __bf16* wqb = (__bf16*)(ws + ((size_t)8  << 20));     // 2 MB
  __bf16* wob = (__bf16*)(ws + ((size_t)10 << 20));     // 2 MB
  __bf16* qb  = (__bf16*)(ws + ((size_t)12 << 20));     // 8 MB  q projection
  __bf16* ab  = (__bf16*)(ws + ((size_t)20 << 20));     // 8 MB  attn output

  const int M = 4096, N = 1024, K = 1024;

  k_cvt<<<(M * K / 4 + 255) / 256, 256, 0, stream>>>(x,  xb,  M * K / 4);
  k_cvt<<<(N * K / 4 + 255) / 256, 256, 0, stream>>>(Wq, wqb, N * K / 4);
  k_cvt<<<(N * K / 4 + 255) / 256, 256, 0, stream>>>(Wo, wob, N * K / 4);

  k_gemm_bt<true ><<<dim3(16, 32), 256, 0, stream>>>(xb, wqb, bq, qb,    M, N, K);
  k_attn          <<<dim3(16, 32), 512, 0, stream>>>(qb, ab);
  k_gemm_bt<false><<<dim3(16, 32), 256, 0, stream>>>(ab, wob, bo, d_out, M, N, K);
}